// Round 4
// baseline (359.062 us; speedup 1.0000x reference)
//
#include <hip/hip_runtime.h>
#include <math.h>

#define CNUM 19
#define NB 4
#define HW 589824            // 768*768
#define NPIX 2359296         // NB*HW
#define TILE 1024            // pixels per block

// ---------------------------------------------------------------- workspace
// Everything is per-class partial sums: weights are applied in k_final, so
// no histogram pre-pass is needed.
struct Ws {
  float S_seg[NB][CNUM];     // sum of -log p_target over valid px with tc==c
  float C_seg[NB][CNUM];     // count of those px (== per-image histogram)
  float S_att[NB][CNUM];     // same, restricted to edge>0.8 px
  float C_att[NB][CNUM];
  float B_pos;               // sum of bce over edgemask==1 px
  float B_neg;               // sum of bce over edgemask==0 px
  unsigned int pos_num;
  unsigned int neg_num;
};

// ---------------------------------------------------------------- init
__global__ void k_init(Ws* ws) {
  unsigned int* p = (unsigned int*)ws;
  const int nw = (int)(sizeof(Ws) / 4);
  for (int i = threadIdx.x; i < nw; i += blockDim.x) p[i] = 0u;
}

// ---------------------------------------------------------------- fused main
// grid (HW/TILE, NB) x 256. Each block: DMA 19 channels x 1024 px into LDS
// via global_load_lds (fire-and-forget, 19 loads in flight per wave), then
// compute log-softmax terms from LDS and accumulate per-class partials.
__global__ __launch_bounds__(256, 2) void k_main(const float* __restrict__ segin,
                                                 const float* __restrict__ edgein,
                                                 const int* __restrict__ segmask,
                                                 const int* __restrict__ edgemask,
                                                 Ws* __restrict__ ws) {
  const int n = blockIdx.y;
  const int tid = threadIdx.x;
  const int wave = tid >> 6;
  const int lane = tid & 63;
  const int tile0 = blockIdx.x * TILE;

  __shared__ float xs[CNUM][TILE];                 // 76 KB channel tile
  __shared__ float aSs[CNUM], aCs[CNUM], aSa[CNUM], aCa[CNUM];
  __shared__ float redf[4][2];
  __shared__ unsigned int redu[4][2];

  if (tid < CNUM) { aSs[tid] = 0.f; aCs[tid] = 0.f; aSa[tid] = 0.f; aCa[tid] = 0.f; }

  // ---- async DMA: per wave, per channel: 64 lanes x 16 B = 1 KB
  {
    const float* g0 = segin + (size_t)n * CNUM * HW + tile0 + wave * 256 + lane * 4;
    #pragma unroll
    for (int c = 0; c < CNUM; ++c) {
      __builtin_amdgcn_global_load_lds(
          (const __attribute__((address_space(1))) void*)(g0 + (size_t)c * HW),
          (__attribute__((address_space(3))) void*)(&xs[c][wave * 256]),
          16, 0, 0);
    }
  }
  // masks: normal vector loads
  const int px = n * HW + tile0 + tid * 4;
  int4   tm = *reinterpret_cast<const int4*>(segmask + px);
  float4 ev = *reinterpret_cast<const float4*>(edgein + px);
  int4   em = *reinterpret_cast<const int4*>(edgemask + px);

  __syncthreads();   // drains vmcnt (DMA + masks), publishes zeroed accums

  int   tarr[4]  = {tm.x, tm.y, tm.z, tm.w};
  float earr[4]  = {ev.x, ev.y, ev.z, ev.w};
  int   emarr[4] = {em.x, em.y, em.z, em.w};
  int tc[4];
  #pragma unroll
  for (int p = 0; p < 4; ++p) tc[p] = min(max(tarr[p], 0), CNUM - 1);

  float s[4]  = {0.f, 0.f, 0.f, 0.f};
  float xt[4] = {0.f, 0.f, 0.f, 0.f};
  #pragma unroll
  for (int c = 0; c < CNUM; ++c) {
    float4 v = *reinterpret_cast<const float4*>(&xs[c][tid * 4]);   // ds_read_b128
    float va[4] = {v.x, v.y, v.z, v.w};
    #pragma unroll
    for (int p = 0; p < 4; ++p) {
      s[p] += __expf(va[p]);
      xt[p] = (tc[p] == c) ? va[p] : xt[p];
    }
  }

  float bp = 0.f, bn = 0.f;
  unsigned int cp = 0u, cn = 0u;
  #pragma unroll
  for (int p = 0; p < 4; ++p) {
    float lp = xt[p] - __logf(s[p]);
    bool valid = (tarr[p] != 255);
    if (valid) {
      atomicAdd(&aSs[tc[p]], -lp);
      atomicAdd(&aCs[tc[p]], 1.f);
      if (earr[p] > 0.8f) {
        atomicAdd(&aSa[tc[p]], -lp);
        atomicAdd(&aCa[tc[p]], 1.f);
      }
    }
    float e = earr[p];
    int emv = emarr[p];
    float bce = fmaxf(e, 0.f) - e * (float)emv + log1pf(__expf(-fabsf(e)));
    bp += (emv == 1) ? bce : 0.f;
    bn += (emv == 0) ? bce : 0.f;
    cp += (emv == 1) ? 1u : 0u;
    cn += (emv == 0) ? 1u : 0u;
  }

  #pragma unroll
  for (int off = 32; off > 0; off >>= 1) {
    bp += __shfl_down(bp, off);
    bn += __shfl_down(bn, off);
    cp += __shfl_down(cp, off);
    cn += __shfl_down(cn, off);
  }
  if (lane == 0) { redf[wave][0] = bp; redf[wave][1] = bn;
                   redu[wave][0] = cp; redu[wave][1] = cn; }
  __syncthreads();   // also makes all LDS class-atomics visible
  if (tid == 0) {
    float tbp = redf[0][0] + redf[1][0] + redf[2][0] + redf[3][0];
    float tbn = redf[0][1] + redf[1][1] + redf[2][1] + redf[3][1];
    unsigned int tcp = redu[0][0] + redu[1][0] + redu[2][0] + redu[3][0];
    unsigned int tcn = redu[0][1] + redu[1][1] + redu[2][1] + redu[3][1];
    atomicAdd(&ws->B_pos, tbp);
    atomicAdd(&ws->B_neg, tbn);
    atomicAdd(&ws->pos_num, tcp);
    atomicAdd(&ws->neg_num, tcn);
  }
  if (tid < CNUM) {
    atomicAdd(&ws->S_seg[n][tid], aSs[tid]);
    atomicAdd(&ws->C_seg[n][tid], aCs[tid]);
    atomicAdd(&ws->S_att[n][tid], aSa[tid]);
    atomicAdd(&ws->C_att[n][tid], aCa[tid]);
  }
}

// ---------------------------------------------------------------- finalize
__global__ void k_final(const Ws* __restrict__ ws, float* __restrict__ out) {
  if (threadIdx.x == 0 && blockIdx.x == 0) {
    double segl = 0.0, attl = 0.0;
    for (int n = 0; n < NB; ++n) {
      double tot = 0.0, num = 0.0, den = 0.0;
      for (int c = 0; c < CNUM; ++c) tot += (double)ws->C_seg[n][c];
      for (int c = 0; c < CNUM; ++c) {
        double b = (double)ws->C_seg[n][c];
        double w = (b != 0.0 ? (1.0 - b / tot) : 0.0) + 1.0;
        num += w * (double)ws->S_seg[n][c];
        den += w * b;
      }
      segl += num / den;
      double tota = 0.0, numa = 0.0, dena = 0.0;
      for (int c = 0; c < CNUM; ++c) tota += (double)ws->C_att[n][c];
      for (int c = 0; c < CNUM; ++c) {
        double b = (double)ws->C_att[n][c];
        double w = (b != 0.0 ? (1.0 - b / tota) : 0.0) + 1.0;
        numa += w * (double)ws->S_att[n][c];
        dena += w * b;
      }
      attl += numa / dena;
    }
    double pos = (double)ws->pos_num, neg = (double)ws->neg_num;
    double wpos = neg / (pos + neg), wneg = pos / (pos + neg);
    double edgel = (wpos * (double)ws->B_pos + wneg * (double)ws->B_neg) / (double)NPIX;
    out[0] = (float)(segl + 0.3 * edgel + 0.1 * attl);
  }
}

// ---------------------------------------------------------------- launch
extern "C" void kernel_launch(void* const* d_in, const int* in_sizes, int n_in,
                              void* d_out, int out_size, void* d_ws, size_t ws_size,
                              hipStream_t stream) {
  const float* segin   = (const float*)d_in[0];
  const float* edgein  = (const float*)d_in[1];
  const int*   segmask = (const int*)d_in[2];
  const int*   edgemask= (const int*)d_in[3];
  Ws* ws = (Ws*)d_ws;
  float* out = (float*)d_out;

  hipLaunchKernelGGL(k_init,  dim3(1),              dim3(128), 0, stream, ws);
  hipLaunchKernelGGL(k_main,  dim3(HW / TILE, NB),  dim3(256), 0, stream,
                     segin, edgein, segmask, edgemask, ws);
  hipLaunchKernelGGL(k_final, dim3(1),              dim3(1),   0, stream, ws, out);
}

// Round 5
// 322.547 us; speedup vs baseline: 1.1132x; 1.1132x over previous
//
#include <hip/hip_runtime.h>
#include <math.h>

#define CNUM 19
#define NB 4
#define HW 589824            // 768*768
#define NPIX 2359296         // NB*HW
#define TPB 128              // threads per block (k_main)
#define PXT 16               // pixels per thread
#define TILE (TPB * PXT)     // 2048 px per block; HW % TILE == 0

// ---------------------------------------------------------------- workspace
struct Ws {
  unsigned int hist_seg[NB][CNUM];
  unsigned int hist_att[NB][CNUM];
  unsigned int pos_num;
  unsigned int neg_num;
  double num_seg[NB];
  double den_seg[NB];
  double num_att[NB];
  double den_att[NB];
  double bce_sum;
};

// ---------------------------------------------------------------- init
__global__ void k_init(Ws* ws) {
  unsigned int* p = (unsigned int*)ws;
  const int nw = (int)(sizeof(Ws) / 4);
  for (int i = threadIdx.x; i < nw; i += blockDim.x) p[i] = 0u;
}

// ---------------------------------------------------------------- histograms
__global__ __launch_bounds__(256) void k_hist(const int* __restrict__ segmask,
                                              const float* __restrict__ edgein,
                                              const int* __restrict__ edgemask,
                                              Ws* __restrict__ ws) {
  const int n  = blockIdx.y;
  const int bx = blockIdx.x;
  const int tid = threadIdx.x;
  const int base = n * HW + bx * 4096 + tid * 4;

  unsigned int cs[CNUM], ca[CNUM];
  #pragma unroll
  for (int c = 0; c < CNUM; ++c) { cs[c] = 0u; ca[c] = 0u; }
  unsigned int cp = 0u, cn = 0u;

  #pragma unroll
  for (int it = 0; it < 4; ++it) {
    const int idx = base + it * 1024;
    int4   sv = *reinterpret_cast<const int4*>(segmask + idx);
    float4 e  = *reinterpret_cast<const float4*>(edgein + idx);
    int4   mv = *reinterpret_cast<const int4*>(edgemask + idx);
    int   sa[4] = {sv.x, sv.y, sv.z, sv.w};
    float ea[4] = {e.x, e.y, e.z, e.w};
    int   ma[4] = {mv.x, mv.y, mv.z, mv.w};
    #pragma unroll
    for (int p = 0; p < 4; ++p) {
      const int s = sa[p];
      const bool inb = ((unsigned)s) < (unsigned)CNUM;
      const unsigned long long attm = __ballot(ea[p] > 0.8f);
      #pragma unroll
      for (int c = 0; c < CNUM; ++c) {
        unsigned long long bm = __ballot(inb && (s == c));
        cs[c] += (unsigned)__popcll(bm);
        ca[c] += (unsigned)__popcll(bm & attm);
      }
      cp += (unsigned)__popcll(__ballot(ma[p] == 1));
      cn += (unsigned)__popcll(__ballot(ma[p] == 0));
    }
  }

  __shared__ unsigned int red[4][2 * CNUM + 2];
  const int wave = tid >> 6;
  const int lane = tid & 63;
  if (lane == 0) {
    #pragma unroll
    for (int c = 0; c < CNUM; ++c) { red[wave][c] = cs[c]; red[wave][CNUM + c] = ca[c]; }
    red[wave][2 * CNUM] = cp;
    red[wave][2 * CNUM + 1] = cn;
  }
  __syncthreads();
  if (tid < 2 * CNUM + 2) {
    unsigned int v = red[0][tid] + red[1][tid] + red[2][tid] + red[3][tid];
    if (tid < CNUM)               atomicAdd(&ws->hist_seg[n][tid], v);
    else if (tid < 2 * CNUM)      atomicAdd(&ws->hist_att[n][tid - CNUM], v);
    else if (tid == 2 * CNUM)     atomicAdd(&ws->pos_num, v);
    else                          atomicAdd(&ws->neg_num, v);
  }
}

// ---------------------------------------------------------------- main pass
// Channel-major: each block covers 2048 consecutive px; per channel it loads
// 8 KB CONTIGUOUS (4 x 2KB coalesced instructions) before moving to the next
// channel. This replaces the 2.3MB-strided 1KB-granule pattern (all 19
// streams aliasing the same L2 slice/set bits) with sequential bursts.
__global__ __launch_bounds__(TPB) void k_main(const float* __restrict__ segin,
                                              const float* __restrict__ edgein,
                                              const int* __restrict__ segmask,
                                              const int* __restrict__ edgemask,
                                              const Ws* __restrict__ ws,
                                              Ws* __restrict__ wsw) {
  const int n = blockIdx.y;
  const int t = threadIdx.x;
  const int tile0 = blockIdx.x * TILE;

  __shared__ float lws[CNUM], lwa[CNUM];
  __shared__ float redlds[2][5];

  if (t < CNUM) {
    float total = 0.f;
    #pragma unroll
    for (int i = 0; i < CNUM; ++i) total += (float)ws->hist_seg[n][i];
    float bins = (float)ws->hist_seg[n][t];
    lws[t] = (bins != 0.f ? (1.0f - bins / total) : 0.f) + 1.0f;
  } else if (t >= 64 && t < 64 + CNUM) {
    int c = t - 64;
    float total = 0.f;
    #pragma unroll
    for (int i = 0; i < CNUM; ++i) total += (float)ws->hist_att[n][i];
    float bins = (float)ws->hist_att[n][c];
    lwa[c] = (bins != 0.f ? (1.0f - bins / total) : 0.f) + 1.0f;
  }
  const unsigned int pn = ws->pos_num, nn = ws->neg_num;
  const float inv_sum = 1.0f / (float)(pn + nn);
  const float wpos = (float)nn * inv_sum;
  const float wneg = (float)pn * inv_sum;
  __syncthreads();

  const int pxbase = n * HW + tile0;

  // masks/edge: issue early (in flight during channel loop). Pack target
  // class + validity + edgemask to keep registers low.
  int tcv[PXT];
  unsigned int validbits = 0u;   // bit p: segmask != 255
  unsigned int embits = 0u;      // 2 bits per p: edgemask value (0/1)
  float4 ev[4];
  #pragma unroll
  for (int k = 0; k < 4; ++k) {
    const int off = pxbase + (k * TPB + t) * 4;
    int4 tm = *reinterpret_cast<const int4*>(segmask + off);
    ev[k]   = *reinterpret_cast<const float4*>(edgein + off);
    int4 em = *reinterpret_cast<const int4*>(edgemask + off);
    int ta[4] = {tm.x, tm.y, tm.z, tm.w};
    int ea[4] = {em.x, em.y, em.z, em.w};
    #pragma unroll
    for (int j = 0; j < 4; ++j) {
      const int p = k * 4 + j;
      tcv[p] = min(max(ta[j], 0), CNUM - 1);
      validbits |= (ta[j] != 255) ? (1u << p) : 0u;
      embits |= ((unsigned)(ea[j] & 3)) << (2 * p);
    }
  }

  float sacc[PXT], xt[PXT];
  #pragma unroll
  for (int p = 0; p < PXT; ++p) { sacc[p] = 0.f; xt[p] = 0.f; }

  const float* cb = segin + (size_t)n * CNUM * HW + tile0;
  #pragma unroll
  for (int c = 0; c < CNUM; ++c) {
    float4 v[4];
    #pragma unroll
    for (int k = 0; k < 4; ++k)
      v[k] = *reinterpret_cast<const float4*>(cb + (size_t)c * HW + (k * TPB + t) * 4);
    #pragma unroll
    for (int k = 0; k < 4; ++k) {
      float va[4] = {v[k].x, v[k].y, v[k].z, v[k].w};
      #pragma unroll
      for (int j = 0; j < 4; ++j) {
        const int p = k * 4 + j;
        sacc[p] += __expf(va[j]);
        xt[p] = (tcv[p] == c) ? va[j] : xt[p];
      }
    }
  }

  float acc_num_s = 0.f, acc_den_s = 0.f, acc_num_a = 0.f, acc_den_a = 0.f, acc_bce = 0.f;
  #pragma unroll
  for (int k = 0; k < 4; ++k) {
    float ea[4] = {ev[k].x, ev[k].y, ev[k].z, ev[k].w};
    #pragma unroll
    for (int j = 0; j < 4; ++j) {
      const int p = k * 4 + j;
      float lp = xt[p] - __logf(sacc[p]);
      bool valid = (validbits >> p) & 1u;
      float pw_s = valid ? lws[tcv[p]] : 0.f;
      acc_num_s -= pw_s * lp;
      acc_den_s += pw_s;

      float e = ea[j];
      bool valida = valid && (e > 0.8f);
      float pw_a = valida ? lwa[tcv[p]] : 0.f;
      acc_num_a -= pw_a * lp;
      acc_den_a += pw_a;

      int emv = (int)((embits >> (2 * p)) & 3u);
      float bce = fmaxf(e, 0.f) - e * (float)emv + log1pf(__expf(-fabsf(e)));
      float wb = (emv == 1) ? wpos : ((emv == 0) ? wneg : 0.f);
      acc_bce += wb * bce;
    }
  }

  #pragma unroll
  for (int off = 32; off > 0; off >>= 1) {
    acc_num_s += __shfl_down(acc_num_s, off);
    acc_den_s += __shfl_down(acc_den_s, off);
    acc_num_a += __shfl_down(acc_num_a, off);
    acc_den_a += __shfl_down(acc_den_a, off);
    acc_bce   += __shfl_down(acc_bce, off);
  }
  const int wave = t >> 6;
  const int lane = t & 63;
  if (lane == 0) {
    redlds[wave][0] = acc_num_s; redlds[wave][1] = acc_den_s;
    redlds[wave][2] = acc_num_a; redlds[wave][3] = acc_den_a;
    redlds[wave][4] = acc_bce;
  }
  __syncthreads();
  if (t == 0) {
    float r0 = redlds[0][0] + redlds[1][0];
    float r1 = redlds[0][1] + redlds[1][1];
    float r2 = redlds[0][2] + redlds[1][2];
    float r3 = redlds[0][3] + redlds[1][3];
    float r4 = redlds[0][4] + redlds[1][4];
    atomicAdd(&wsw->num_seg[n], (double)r0);
    atomicAdd(&wsw->den_seg[n], (double)r1);
    atomicAdd(&wsw->num_att[n], (double)r2);
    atomicAdd(&wsw->den_att[n], (double)r3);
    atomicAdd(&wsw->bce_sum,    (double)r4);
  }
}

// ---------------------------------------------------------------- finalize
__global__ void k_final(const Ws* __restrict__ ws, float* __restrict__ out) {
  if (threadIdx.x == 0 && blockIdx.x == 0) {
    double segl = 0.0, attl = 0.0;
    for (int i = 0; i < NB; ++i) {
      segl += ws->num_seg[i] / ws->den_seg[i];
      attl += ws->num_att[i] / ws->den_att[i];
    }
    double edgel = ws->bce_sum / (double)NPIX;
    out[0] = (float)(segl + 0.3 * edgel + 0.1 * attl);
  }
}

// ---------------------------------------------------------------- launch
extern "C" void kernel_launch(void* const* d_in, const int* in_sizes, int n_in,
                              void* d_out, int out_size, void* d_ws, size_t ws_size,
                              hipStream_t stream) {
  const float* segin   = (const float*)d_in[0];
  const float* edgein  = (const float*)d_in[1];
  const int*   segmask = (const int*)d_in[2];
  const int*   edgemask= (const int*)d_in[3];
  Ws* ws = (Ws*)d_ws;
  float* out = (float*)d_out;

  hipLaunchKernelGGL(k_init,  dim3(1),              dim3(128), 0, stream, ws);
  hipLaunchKernelGGL(k_hist,  dim3(HW / 4096, NB),  dim3(256), 0, stream, segmask, edgein, edgemask, ws);
  hipLaunchKernelGGL(k_main,  dim3(HW / TILE, NB),  dim3(TPB), 0, stream, segin, edgein, segmask, edgemask, ws, ws);
  hipLaunchKernelGGL(k_final, dim3(1),              dim3(1),   0, stream, ws, out);
}